// Round 25
// baseline (114.384 us; speedup 1.0000x reference)
//
#include <hip/hip_runtime.h>
#include <cmath>

#define CIN   512
#define COUT  64
#define DBINS 41
#define NFEAT 105   // DBINS + COUT
#define HF    16
#define WF    44
#define NPIX  704   // HF*WF
#define NCAM  24    // B*N
#define NXG   128
#define NVOX  16384 // 128*128 (NX2 == 1)
#define ROWF  210   // per-pixel feat row (layout kept; only [0..145] used now)
#define NPAIR (NCAM * NPIX * DBINS)  // 692736
#define NSUB  16
#define NCNT  (NVOX * NSUB)          // 262144 sub-counters
#define GEMM_BLOCKS 1848             // 132 tiles x 14 oh
#define ZERO_BLOCKS 320

// Counter layout: sub-major (validated r17). Run-merge at heads (r22).
// Dense bev (r23). Fused setup/zero into gemm dispatch (r24).
// GEMM: G=2 uniform-w rate 1/(4G) is O-independent -> O=2 lets full K=512
// keep 1848 blocks (7.2/CU) with NO kh split: feat written once.

// Workspace layout (bytes):
#define WS_BSUM  5120
#define WS_FEAT  8192
#define WS_OFFS  14200832
#define WS_REC   15249408
#define WS_CNT   15249408
#define WS_BEV   18020352

// ---------------------------------------------------------------- utilities
__device__ __forceinline__ void inv3(const double a[9], double o[9]) {
    double c00 =  a[4]*a[8] - a[5]*a[7];
    double c01 = -(a[3]*a[8] - a[5]*a[6]);
    double c02 =  a[3]*a[7] - a[4]*a[6];
    double det = a[0]*c00 + a[1]*c01 + a[2]*c02;
    double id  = 1.0 / det;
    o[0] = c00 * id;
    o[1] = -(a[1]*a[8] - a[2]*a[7]) * id;
    o[2] =  (a[1]*a[5] - a[2]*a[4]) * id;
    o[3] = c01 * id;
    o[4] =  (a[0]*a[8] - a[2]*a[6]) * id;
    o[5] = -(a[0]*a[5] - a[2]*a[3]) * id;
    o[6] = c02 * id;
    o[7] = -(a[0]*a[7] - a[1]*a[6]) * id;
    o[8] =  (a[0]*a[4] - a[1]*a[3]) * id;
}

// --------------------------- 1x1 conv GEMM + fused setup/zero (extra blocks)
// GEMM: M=128 px (G=2), N=8 outs (4 waves x O=2), FULL K=512 (BK=16, 32 kt).
// oh bases {0,8,...,96, 97}: rows 97..103 computed twice bitwise-identically.
// Per-kq rates: 2 ds_read + 2 uniform w per 16 FMA-instr/thread = validated
// 1/(4G) ratio. Blocks >= GEMM_BLOCKS zero cnt16/bev + build cams.
__global__ __launch_bounds__(256) void gemm_setup_k(const float* __restrict__ x,
                                                    const float* __restrict__ w,
                                                    const float* __restrict__ bias,
                                                    float* __restrict__ feat,
                                                    const float* __restrict__ rots,
                                                    const float* __restrict__ trans,
                                                    const float* __restrict__ intrins,
                                                    const float* __restrict__ post_rots,
                                                    const float* __restrict__ post_trans,
                                                    double* __restrict__ cams,
                                                    int* __restrict__ cnt16,
                                                    float* __restrict__ bev) {
    if (blockIdx.x >= GEMM_BLOCKS) {
        int zb = blockIdx.x - GEMM_BLOCKS;      // 0..319
        int4 z = make_int4(0, 0, 0, 0);
        if (zb < 64) {
            int base = (zb * 256 + threadIdx.x) * 16;
            #pragma unroll
            for (int j = 0; j < 4; ++j)
                *reinterpret_cast<int4*>(&cnt16[base + j * 4]) = z;
        } else {
            int base = ((zb - 64) * 256 + threadIdx.x) * 16;
            #pragma unroll
            for (int j = 0; j < 4; ++j)
                *reinterpret_cast<int4*>(&bev[base + j * 4]) = z;
        }
        if (zb == 0 && threadIdx.x < NCAM) {
            int i = threadIdx.x;
            double R[9], K[9], PR[9], Kinv[9], PRinv[9];
            for (int k = 0; k < 9; ++k) {
                R[k]  = (double)rots[i*9 + k];
                K[k]  = (double)intrins[i*9 + k];
                PR[k] = (double)post_rots[i*9 + k];
            }
            inv3(K, Kinv);
            inv3(PR, PRinv);
            double* o = cams + (size_t)i * 24;
            for (int k = 0; k < 9; ++k) o[k] = PRinv[k];
            o[9]  = (double)post_trans[i*3 + 0];
            o[10] = (double)post_trans[i*3 + 1];
            o[11] = (double)post_trans[i*3 + 2];
            for (int r = 0; r < 3; ++r)
                for (int c = 0; c < 3; ++c)
                    o[12 + r*3 + c] = R[r*3+0]*Kinv[0*3+c] + R[r*3+1]*Kinv[1*3+c] + R[r*3+2]*Kinv[2*3+c];
            o[21] = (double)trans[i*3 + 0];
            o[22] = (double)trans[i*3 + 1];
            o[23] = (double)trans[i*3 + 2];
        }
        return;
    }

    __shared__ float smem[4096];

    int bx   = blockIdx.x;            // 0..1847
    int oh   = bx % 14;
    int tile = bx / 14;               // 0..131
    int p0g  = tile * 128;
    int lane = threadIdx.x & 63;
    int wid  = threadIdx.x >> 6;      // 0..3
    int obase0 = (oh < 13) ? oh * 8 : 97;   // 0,8,...,96,97

    int og = obase0 + wid * 2;        // wave's 2 output rows
    const float* wbase = w + (size_t)__builtin_amdgcn_readfirstlane(og) * CIN;

    int spx  = threadIdx.x & 127;
    int skq  = threadIdx.x >> 7;      // 0..1
    int gpix = p0g + spx;
    int sbn  = gpix / NPIX;
    int sp   = gpix - sbn * NPIX;
    const float* gx = x + (size_t)sbn * CIN * NPIX + sp;

    float xr[2][4];
    float acc[2][2];
    #pragma unroll
    for (int i = 0; i < 2; ++i)
        #pragma unroll
        for (int j = 0; j < 2; ++j) acc[i][j] = 0.0f;

    // ---- prologue: stage kt=0 into buf0, then issue kt=1 loads into xr
    #pragma unroll
    for (int q = 0; q < 2; ++q)
        #pragma unroll
        for (int c = 0; c < 4; ++c)
            xr[q][c] = gx[(size_t)((skq + 2 * q) * 4 + c) * NPIX];
    #pragma unroll
    for (int q = 0; q < 2; ++q)
        *reinterpret_cast<float4*>(&smem[((skq + 2 * q) * 128 + spx) * 4]) =
            make_float4(xr[q][0], xr[q][1], xr[q][2], xr[q][3]);
    #pragma unroll
    for (int q = 0; q < 2; ++q)
        #pragma unroll
        for (int c = 0; c < 4; ++c)
            xr[q][c] = gx[(size_t)(16 + (skq + 2 * q) * 4 + c) * NPIX];
    __syncthreads();

    #pragma unroll 1
    for (int kt = 0; kt < 32; ++kt) {         // BK=16, K=512
        int cur = kt & 1;
        if (kt < 31) {
            float* xsn = smem + (cur ^ 1) * 2048;
            #pragma unroll
            for (int q = 0; q < 2; ++q)
                *reinterpret_cast<float4*>(&xsn[((skq + 2 * q) * 128 + spx) * 4]) =
                    make_float4(xr[q][0], xr[q][1], xr[q][2], xr[q][3]);
        }
        if (kt < 30) {
            #pragma unroll
            for (int q = 0; q < 2; ++q)
                #pragma unroll
                for (int c = 0; c < 4; ++c)
                    xr[q][c] = gx[(size_t)((kt + 2) * 16 + (skq + 2 * q) * 4 + c) * NPIX];
        }
        const float* xs = smem + cur * 2048;
        const float* wk = wbase + kt * 16;
        #pragma unroll
        for (int kq = 0; kq < 4; ++kq) {
            float4 xv[2];
            #pragma unroll
            for (int j = 0; j < 2; ++j)
                xv[j] = *reinterpret_cast<const float4*>(&xs[(kq * 128 + lane + j * 64) * 4]);
            #pragma unroll
            for (int i = 0; i < 2; ++i) {
                float4 wv = *reinterpret_cast<const float4*>(wk + (size_t)i * CIN + (kq << 2));
                #pragma unroll
                for (int j = 0; j < 2; ++j) {
                    acc[i][j] = fmaf(xv[j].x, wv.x, acc[i][j]);
                    acc[i][j] = fmaf(xv[j].y, wv.y, acc[i][j]);
                    acc[i][j] = fmaf(xv[j].z, wv.z, acc[i][j]);
                    acc[i][j] = fmaf(xv[j].w, wv.w, acc[i][j]);
                }
            }
        }
        __syncthreads();
    }

    // ---- epilogue: LDS transpose tile [128][9] (odd stride), coalesced store
    float* ep = smem;
    #pragma unroll
    for (int i = 0; i < 2; ++i) {
        int o = obase0 + wid * 2 + i;
        #pragma unroll
        for (int j = 0; j < 2; ++j)
            ep[(lane + j * 64) * 9 + wid * 2 + i] = acc[i][j] + bias[o];
    }
    __syncthreads();
    for (int idx = threadIdx.x; idx < 128 * 8; idx += 256) {
        int px = idx >> 3;
        int ol = idx & 7;
        feat[(size_t)(p0g + px) * ROWF + obase0 + ol] = ep[px * 9 + ol];
    }
}

// -------------------------------------------- softmax + geometry, in-place
// 8 waves/block (r24); NO kh fold (feat holds one K=512 result — r19 path).
__global__ __launch_bounds__(512) void phaseA_k(float* __restrict__ feat,
                                                const double* __restrict__ cams,
                                                int* __restrict__ cnt16) {
    int wid  = threadIdx.x >> 6;
    int lane = threadIdx.x & 63;
    int pix  = blockIdx.x * 8 + wid;
    int bn   = pix / NPIX;
    int p    = pix - bn * NPIX;
    int h    = p / WF;
    int wpx  = p - h * WF;

    __shared__ float f[8][NFEAT];
    float* row = feat + (size_t)pix * ROWF;
    for (int o = lane; o < NFEAT; o += 64) f[wid][o] = row[o];
    __syncthreads();

    float v = (lane < DBINS) ? f[wid][lane] : -1e30f;
    float m = v;
    #pragma unroll
    for (int o = 32; o > 0; o >>= 1) m = fmaxf(m, __shfl_xor(m, o, 64));
    float e = (lane < DBINS) ? expf(v - m) : 0.0f;
    float s = e;
    #pragma unroll
    for (int o = 32; o > 0; o >>= 1) s += __shfl_xor(s, o, 64);

    int   rk = -1;
    float pd = 0.0f;
    if (lane < DBINS) {
        pd = e / s;
        const double* cm = cams + (size_t)bn * 24;
        double dd = 4.0 + (double)lane;
        double ax = (double)wpx - cm[9];
        double ay = (double)h   - cm[10];
        double az = dd          - cm[11];
        double q0 = cm[0]*ax + cm[1]*ay + cm[2]*az;
        double q1 = cm[3]*ax + cm[4]*ay + cm[5]*az;
        double q2 = cm[6]*ax + cm[7]*ay + cm[8]*az;
        double r0 = q0 * q2, r1 = q1 * q2, r2 = q2;
        double sx = cm[12]*r0 + cm[13]*r1 + cm[14]*r2 + cm[21];
        double sy = cm[15]*r0 + cm[16]*r1 + cm[17]*r2 + cm[22];
        double sz = cm[18]*r0 + cm[19]*r1 + cm[20]*r2 + cm[23];
        int cx = (int)((sx + 50.8) / 0.8);   // trunc == .astype(int32)
        int cy = (int)((sy + 50.8) / 0.8);
        int cz = (int)(sz / 20.0);
        bool ok = (cx >= 0) && (cx < NXG) && (cy >= 0) && (cy < NXG) && (cz == 0);
        rk = ok ? (cy * NXG + cx) : -1;
    }
    int  rkprev = __shfl_up(rk, 1, 64);
    bool head   = (rk >= 0) && (lane == 0 || rk != rkprev);

    if (lane < DBINS) {
        row[64 + lane] = pd;
        ((int*)row)[105 + lane] = rk;
    }
    if (head) atomicAdd(&cnt16[(pix & 15) * NVOX + rk], 1);   // sub-major, heads only
    row[lane] = f[wid][DBINS + lane];
}

// ----------------------------------------- scan of 262144 counters (2 stages)
__device__ __forceinline__ int physidx(int l) { return (l & 15) * NVOX + (l >> 4); }

__global__ __launch_bounds__(256) void scan1_k(const int* __restrict__ cnt,
                                               int* __restrict__ bsum) {
    __shared__ int sc[256];
    int t = threadIdx.x;
    int base = blockIdx.x * 1024 + t * 4;
    int s = 0;
    #pragma unroll
    for (int j = 0; j < 4; ++j) s += cnt[physidx(base + j)];
    sc[t] = s;
    __syncthreads();
    for (int off = 128; off > 0; off >>= 1) {
        if (t < off) sc[t] += sc[t + off];
        __syncthreads();
    }
    if (t == 0) bsum[blockIdx.x] = sc[0];
}

__global__ __launch_bounds__(256) void scan3_k(const int* __restrict__ cnt,
                                               const int* __restrict__ bsum,
                                               int* __restrict__ offs) {
    __shared__ int sb[256];
    __shared__ int sc[256];
    int t = threadIdx.x;
    sb[t] = bsum[t];
    __syncthreads();
    for (int off = 1; off < 256; off <<= 1) {
        int a = (t >= off) ? sb[t - off] : 0;
        __syncthreads();
        sb[t] += a;
        __syncthreads();
    }
    int bbase = sb[blockIdx.x] - bsum[blockIdx.x];

    int base = blockIdx.x * 1024 + t * 4;
    int loc[4];
    int s = 0;
    #pragma unroll
    for (int j = 0; j < 4; ++j) { loc[j] = cnt[physidx(base + j)]; s += loc[j]; }
    sc[t] = s;
    __syncthreads();
    for (int off = 1; off < 256; off <<= 1) {
        int a = (t >= off) ? sc[t - off] : 0;
        __syncthreads();
        sc[t] += a;
        __syncthreads();
    }
    int run = bbase + sc[t] - s;
    #pragma unroll
    for (int j = 0; j < 4; ++j) { offs[physidx(base + j)] = run; run += loc[j]; }
}

// --------------------------------- place runs (head-merged) into segments
__global__ __launch_bounds__(256) void place_k(float* __restrict__ feat,
                                               int* __restrict__ offs16,
                                               unsigned* __restrict__ rec) {
    int i = blockIdx.x * 256 + threadIdx.x;
    if (i >= NPAIR) return;
    int pix = i / DBINS;
    int d   = i - pix * DBINS;
    float* row = feat + (size_t)pix * ROWF;
    const int* rowI = (const int*)row;
    int r = rowI[105 + d];
    if (r < 0) return;
    if (d > 0 && rowI[105 + d - 1] == r) return;      // not a run head
    float wsum = row[64 + d];
    for (int j = d + 1; j < DBINS && rowI[105 + j] == r; ++j)
        wsum += row[64 + j];
    row[64 + d] = wsum;                               // merged weight at head
    int pos = atomicAdd(&offs16[(pix & 15) * NVOX + r], 1);   // sub-major
    rec[pos] = ((unsigned)pix << 6) | (unsigned)d;
}

// ------------------------------------- entry-parallel segmented combine
__global__ __launch_bounds__(256) void combine_k(const float* __restrict__ feat,
                                                 const int* __restrict__ offs16,
                                                 const unsigned* __restrict__ rec,
                                                 float* __restrict__ bev) {
    int ncnt = offs16[NCNT - 1];
    int lane = threadIdx.x & 63;
    int wave = (blockIdx.x << 2) + (threadIdx.x >> 6);
    int nwav = gridDim.x << 2;
    int nchunk = (ncnt + 31) >> 5;

    for (int ch = wave; ch < nchunk; ch += nwav) {
        int i0 = ch << 5;
        int n  = min(32, ncnt - i0);
        int   rv = -1, pv = 0;
        float wv = 0.0f;
        if (lane < n) {
            unsigned e = rec[i0 + lane];
            pv = (int)(e >> 6);
            int d = (int)(e & 63u);
            const float* row = feat + (size_t)pv * ROWF;
            rv = ((const int*)row)[105 + d];
            wv = row[64 + d];
        }
        float acc = 0.0f;
        if (n == 32) {
            float xv[32];
            #pragma unroll
            for (int j = 0; j < 32; ++j) {
                int pj = __shfl(pv, j, 64);
                xv[j] = feat[(size_t)pj * ROWF + lane];
            }
            #pragma unroll
            for (int j = 0; j < 32; ++j) {
                int   rj = __shfl(rv, j, 64);
                float wj = __shfl(wv, j, 64);
                acc = fmaf(wj, xv[j], acc);
                int rn = __shfl(rv, (j + 1) & 31, 64);
                if (j == 31 || rn != rj) {
                    atomicAdd(&bev[(size_t)rj * COUT + lane], acc);
                    acc = 0.0f;
                }
            }
        } else {
            for (int j = 0; j < n; ++j) {
                int   rj = __shfl(rv, j, 64);
                float wj = __shfl(wv, j, 64);
                int   pj = __shfl(pv, j, 64);
                acc = fmaf(wj, feat[(size_t)pj * ROWF + lane], acc);
                int rn = __shfl(rv, (j + 1) & 31, 64);
                if (j == n - 1 || rn != rj) {
                    atomicAdd(&bev[(size_t)rj * COUT + lane], acc);
                    acc = 0.0f;
                }
            }
        }
    }
}

// -------------------------------------------------------- bev -> out
__global__ __launch_bounds__(256) void transpose_k(const float* __restrict__ bev,
                                                   float* __restrict__ out) {
    __shared__ float t[64][65];
    int r0 = blockIdx.x * 64;
    int c  = threadIdx.x & 63;
    int r4 = threadIdx.x >> 6;
    #pragma unroll
    for (int i = 0; i < 16; ++i) {
        int r = r4 + i * 4;
        t[r][c] = bev[(size_t)(r0 + r) * COUT + c];
    }
    __syncthreads();
    int rl  = threadIdx.x & 63;
    int cc0 = threadIdx.x >> 6;
    #pragma unroll
    for (int i = 0; i < 16; ++i) {
        int ch = cc0 + i * 4;
        out[(size_t)ch * NVOX + r0 + rl] = t[rl][ch];
    }
}

// --------------------------------------------------------------------- launch
extern "C" void kernel_launch(void* const* d_in, const int* in_sizes, int n_in,
                              void* d_out, int out_size, void* d_ws, size_t ws_size,
                              hipStream_t stream) {
    const float* img   = (const float*)d_in[0];
    const float* dw    = (const float*)d_in[1];
    const float* db    = (const float*)d_in[2];
    const float* rots  = (const float*)d_in[3];
    const float* trans = (const float*)d_in[4];
    const float* intr  = (const float*)d_in[5];
    const float* prot  = (const float*)d_in[6];
    const float* ptrn  = (const float*)d_in[7];
    float* out = (float*)d_out;

    char* ws = (char*)d_ws;
    double*   cams   = (double*)ws;
    int*      bsum   = (int*)(ws + WS_BSUM);
    float*    feat   = (float*)(ws + WS_FEAT);
    int*      offs16 = (int*)(ws + WS_OFFS);
    unsigned* rec    = (unsigned*)(ws + WS_REC);
    int*      cnt16  = (int*)(ws + WS_CNT);   // aliases rec (dead before rec use)
    float*    bev    = (float*)(ws + WS_BEV);

    gemm_setup_k<<<GEMM_BLOCKS + ZERO_BLOCKS, 256, 0, stream>>>(
        img, dw, db, feat, rots, trans, intr, prot, ptrn, cams, cnt16, bev);
    phaseA_k<<<NCAM * NPIX / 8, 512, 0, stream>>>(feat, cams, cnt16);
    scan1_k<<<256, 256, 0, stream>>>(cnt16, bsum);
    scan3_k<<<256, 256, 0, stream>>>(cnt16, bsum, offs16);
    place_k<<<(NPAIR + 255) / 256, 256, 0, stream>>>(feat, offs16, rec);
    combine_k<<<3072, 256, 0, stream>>>(feat, offs16, rec, bev);
    transpose_k<<<NVOX / 64, 256, 0, stream>>>(bev, out);
}

// Round 26
// 101.948 us; speedup vs baseline: 1.1220x; 1.1220x over previous
//
#include <hip/hip_runtime.h>
#include <cmath>

#define CIN   512
#define COUT  64
#define DBINS 41
#define NFEAT 105   // DBINS + COUT
#define HF    16
#define WF    44
#define NPIX  704   // HF*WF
#define NCAM  24    // B*N
#define NXG   128
#define NVOX  16384 // 128*128 (NX2 == 1)
#define ROWF  210   // per-pixel feat row
#define NPAIR (NCAM * NPIX * DBINS)  // 692736
#define NSUB  16
#define NCNT  (NVOX * NSUB)          // 262144 sub-counters
#define GEMM_BLOCKS 1848
#define ZERO_BLOCKS 320

// Counter layout: PHYSICAL index = sub*NVOX + rank (sub-major) — validated r17.
// LOGICAL index (scan order, rank-major) l -> phys: (l&15)*NVOX + (l>>4).
// Run-merge at ray heads — validated r22. Dense bev buffer — validated r23.
// Fused setup/zero into gemm dispatch — validated r24.
// GEMM lessons: G=2 uniform-w rate (r17-19), >=4 blocks/CU (r15-16), and the
// kh split HALVES redundant x fetch across oh-splits (r25: removing it
// doubled FETCH 69->138 MB, +12 µs). This is the r24-validated optimum.

// Workspace layout (bytes):
#define WS_BSUM  5120
#define WS_FEAT  8192
#define WS_OFFS  14200832
#define WS_REC   15249408
#define WS_CNT   15249408
#define WS_BEV   18020352

// ---------------------------------------------------------------- utilities
__device__ __forceinline__ void inv3(const double a[9], double o[9]) {
    double c00 =  a[4]*a[8] - a[5]*a[7];
    double c01 = -(a[3]*a[8] - a[5]*a[6]);
    double c02 =  a[3]*a[7] - a[4]*a[6];
    double det = a[0]*c00 + a[1]*c01 + a[2]*c02;
    double id  = 1.0 / det;
    o[0] = c00 * id;
    o[1] = -(a[1]*a[8] - a[2]*a[7]) * id;
    o[2] =  (a[1]*a[5] - a[2]*a[4]) * id;
    o[3] = c01 * id;
    o[4] =  (a[0]*a[8] - a[2]*a[6]) * id;
    o[5] = -(a[0]*a[5] - a[2]*a[3]) * id;
    o[6] = c02 * id;
    o[7] = -(a[0]*a[7] - a[1]*a[6]) * id;
    o[8] =  (a[0]*a[4] - a[1]*a[3]) * id;
}

// --------------------------- 1x1 conv GEMM + fused setup/zero (extra blocks)
// Blocks < GEMM_BLOCKS: r21-validated GEMM (M=128/G=2/N=16, kh split, 7 oh).
// Blocks >= GEMM_BLOCKS (320 of them): zero cnt16 + bev; first zero-block's
// lanes <24 build camera matrices. All independent of the GEMM work.
__global__ __launch_bounds__(256) void gemm_setup_k(const float* __restrict__ x,
                                                    const float* __restrict__ w,
                                                    const float* __restrict__ bias,
                                                    float* __restrict__ feat,
                                                    const float* __restrict__ rots,
                                                    const float* __restrict__ trans,
                                                    const float* __restrict__ intrins,
                                                    const float* __restrict__ post_rots,
                                                    const float* __restrict__ post_trans,
                                                    double* __restrict__ cams,
                                                    int* __restrict__ cnt16,
                                                    float* __restrict__ bev) {
    if (blockIdx.x >= GEMM_BLOCKS) {
        int zb = blockIdx.x - GEMM_BLOCKS;      // 0..319
        int4 z = make_int4(0, 0, 0, 0);
        if (zb < 64) {
            int base = (zb * 256 + threadIdx.x) * 16;
            #pragma unroll
            for (int j = 0; j < 4; ++j)
                *reinterpret_cast<int4*>(&cnt16[base + j * 4]) = z;
        } else {
            int base = ((zb - 64) * 256 + threadIdx.x) * 16;
            #pragma unroll
            for (int j = 0; j < 4; ++j)
                *reinterpret_cast<int4*>(&bev[base + j * 4]) = z;
        }
        if (zb == 0 && threadIdx.x < NCAM) {
            int i = threadIdx.x;
            double R[9], K[9], PR[9], Kinv[9], PRinv[9];
            for (int k = 0; k < 9; ++k) {
                R[k]  = (double)rots[i*9 + k];
                K[k]  = (double)intrins[i*9 + k];
                PR[k] = (double)post_rots[i*9 + k];
            }
            inv3(K, Kinv);
            inv3(PR, PRinv);
            double* o = cams + (size_t)i * 24;
            for (int k = 0; k < 9; ++k) o[k] = PRinv[k];
            o[9]  = (double)post_trans[i*3 + 0];
            o[10] = (double)post_trans[i*3 + 1];
            o[11] = (double)post_trans[i*3 + 2];
            for (int r = 0; r < 3; ++r)
                for (int c = 0; c < 3; ++c)
                    o[12 + r*3 + c] = R[r*3+0]*Kinv[0*3+c] + R[r*3+1]*Kinv[1*3+c] + R[r*3+2]*Kinv[2*3+c];
            o[21] = (double)trans[i*3 + 0];
            o[22] = (double)trans[i*3 + 1];
            o[23] = (double)trans[i*3 + 2];
        }
        return;
    }

    __shared__ float smem[4096];

    int bx   = blockIdx.x;
    int kh   = bx & 1;
    int oh   = (bx >> 1) % 7;
    int tile = (bx >> 1) / 7;
    int p0g  = tile * 128;
    int lane = threadIdx.x & 63;
    int wid  = threadIdx.x >> 6;
    int obase0 = (oh < 6) ? oh * 16 : 89;

    int og = obase0 + wid * 4;
    const float* wbase = w + (size_t)__builtin_amdgcn_readfirstlane(og) * CIN + kh * 256;

    int spx  = threadIdx.x & 127;
    int skq  = threadIdx.x >> 7;
    int gpix = p0g + spx;
    int sbn  = gpix / NPIX;
    int sp   = gpix - sbn * NPIX;
    const float* gx = x + ((size_t)sbn * CIN + kh * 256) * NPIX + sp;

    float xr[2][4];
    float acc[4][2];
    #pragma unroll
    for (int i = 0; i < 4; ++i)
        #pragma unroll
        for (int j = 0; j < 2; ++j) acc[i][j] = 0.0f;

    #pragma unroll
    for (int q = 0; q < 2; ++q)
        #pragma unroll
        for (int c = 0; c < 4; ++c)
            xr[q][c] = gx[(size_t)((skq + 2 * q) * 4 + c) * NPIX];
    #pragma unroll
    for (int q = 0; q < 2; ++q)
        *reinterpret_cast<float4*>(&smem[((skq + 2 * q) * 128 + spx) * 4]) =
            make_float4(xr[q][0], xr[q][1], xr[q][2], xr[q][3]);
    #pragma unroll
    for (int q = 0; q < 2; ++q)
        #pragma unroll
        for (int c = 0; c < 4; ++c)
            xr[q][c] = gx[(size_t)(16 + (skq + 2 * q) * 4 + c) * NPIX];
    __syncthreads();

    #pragma unroll 1
    for (int kt = 0; kt < 16; ++kt) {
        int cur = kt & 1;
        if (kt < 15) {
            float* xsn = smem + (cur ^ 1) * 2048;
            #pragma unroll
            for (int q = 0; q < 2; ++q)
                *reinterpret_cast<float4*>(&xsn[((skq + 2 * q) * 128 + spx) * 4]) =
                    make_float4(xr[q][0], xr[q][1], xr[q][2], xr[q][3]);
        }
        if (kt < 14) {
            #pragma unroll
            for (int q = 0; q < 2; ++q)
                #pragma unroll
                for (int c = 0; c < 4; ++c)
                    xr[q][c] = gx[(size_t)((kt + 2) * 16 + (skq + 2 * q) * 4 + c) * NPIX];
        }
        const float* xs = smem + cur * 2048;
        const float* wk = wbase + kt * 16;
        #pragma unroll
        for (int kq = 0; kq < 4; ++kq) {
            float4 xv[2];
            #pragma unroll
            for (int j = 0; j < 2; ++j)
                xv[j] = *reinterpret_cast<const float4*>(&xs[(kq * 128 + lane + j * 64) * 4]);
            #pragma unroll
            for (int i = 0; i < 4; ++i) {
                float4 wv = *reinterpret_cast<const float4*>(wk + (size_t)i * CIN + (kq << 2));
                #pragma unroll
                for (int j = 0; j < 2; ++j) {
                    acc[i][j] = fmaf(xv[j].x, wv.x, acc[i][j]);
                    acc[i][j] = fmaf(xv[j].y, wv.y, acc[i][j]);
                    acc[i][j] = fmaf(xv[j].z, wv.z, acc[i][j]);
                    acc[i][j] = fmaf(xv[j].w, wv.w, acc[i][j]);
                }
            }
        }
        __syncthreads();
    }

    float* ep = smem;
    #pragma unroll
    for (int i = 0; i < 4; ++i) {
        int o = obase0 + wid * 4 + i;
        float b = (kh == 0) ? bias[o] : 0.0f;
        #pragma unroll
        for (int j = 0; j < 2; ++j)
            ep[(lane + j * 64) * 17 + wid * 4 + i] = acc[i][j] + b;
    }
    __syncthreads();
    for (int idx = threadIdx.x; idx < 128 * 16; idx += 256) {
        int px = idx >> 4;
        int ol = idx & 15;
        feat[(size_t)(p0g + px) * ROWF + kh * NFEAT + obase0 + ol] = ep[px * 17 + ol];
    }
}

// -------------------------------------------- softmax + geometry, in-place
// 8 independent waves per block (one pixel each); kh fold restored (r24).
__global__ __launch_bounds__(512) void phaseA_k(float* __restrict__ feat,
                                                const double* __restrict__ cams,
                                                int* __restrict__ cnt16) {
    int wid  = threadIdx.x >> 6;
    int lane = threadIdx.x & 63;
    int pix  = blockIdx.x * 8 + wid;
    int bn   = pix / NPIX;
    int p    = pix - bn * NPIX;
    int h    = p / WF;
    int wpx  = p - h * WF;

    __shared__ float f[8][NFEAT];
    float* row = feat + (size_t)pix * ROWF;
    for (int o = lane; o < NFEAT; o += 64) f[wid][o] = row[o] + row[NFEAT + o];
    __syncthreads();

    float v = (lane < DBINS) ? f[wid][lane] : -1e30f;
    float m = v;
    #pragma unroll
    for (int o = 32; o > 0; o >>= 1) m = fmaxf(m, __shfl_xor(m, o, 64));
    float e = (lane < DBINS) ? expf(v - m) : 0.0f;
    float s = e;
    #pragma unroll
    for (int o = 32; o > 0; o >>= 1) s += __shfl_xor(s, o, 64);

    int   rk = -1;
    float pd = 0.0f;
    if (lane < DBINS) {
        pd = e / s;
        const double* cm = cams + (size_t)bn * 24;
        double dd = 4.0 + (double)lane;
        double ax = (double)wpx - cm[9];
        double ay = (double)h   - cm[10];
        double az = dd          - cm[11];
        double q0 = cm[0]*ax + cm[1]*ay + cm[2]*az;
        double q1 = cm[3]*ax + cm[4]*ay + cm[5]*az;
        double q2 = cm[6]*ax + cm[7]*ay + cm[8]*az;
        double r0 = q0 * q2, r1 = q1 * q2, r2 = q2;
        double sx = cm[12]*r0 + cm[13]*r1 + cm[14]*r2 + cm[21];
        double sy = cm[15]*r0 + cm[16]*r1 + cm[17]*r2 + cm[22];
        double sz = cm[18]*r0 + cm[19]*r1 + cm[20]*r2 + cm[23];
        int cx = (int)((sx + 50.8) / 0.8);   // trunc == .astype(int32)
        int cy = (int)((sy + 50.8) / 0.8);
        int cz = (int)(sz / 20.0);
        bool ok = (cx >= 0) && (cx < NXG) && (cy >= 0) && (cy < NXG) && (cz == 0);
        rk = ok ? (cy * NXG + cx) : -1;
    }
    int  rkprev = __shfl_up(rk, 1, 64);
    bool head   = (rk >= 0) && (lane == 0 || rk != rkprev);

    if (lane < DBINS) {
        row[64 + lane] = pd;
        ((int*)row)[105 + lane] = rk;
    }
    if (head) atomicAdd(&cnt16[(pix & 15) * NVOX + rk], 1);   // sub-major, heads only
    row[lane] = f[wid][DBINS + lane];
}

// ----------------------------------------- scan of 262144 counters (2 stages)
__device__ __forceinline__ int physidx(int l) { return (l & 15) * NVOX + (l >> 4); }

__global__ __launch_bounds__(256) void scan1_k(const int* __restrict__ cnt,
                                               int* __restrict__ bsum) {
    __shared__ int sc[256];
    int t = threadIdx.x;
    int base = blockIdx.x * 1024 + t * 4;
    int s = 0;
    #pragma unroll
    for (int j = 0; j < 4; ++j) s += cnt[physidx(base + j)];
    sc[t] = s;
    __syncthreads();
    for (int off = 128; off > 0; off >>= 1) {
        if (t < off) sc[t] += sc[t + off];
        __syncthreads();
    }
    if (t == 0) bsum[blockIdx.x] = sc[0];
}

__global__ __launch_bounds__(256) void scan3_k(const int* __restrict__ cnt,
                                               const int* __restrict__ bsum,
                                               int* __restrict__ offs) {
    __shared__ int sb[256];
    __shared__ int sc[256];
    int t = threadIdx.x;
    sb[t] = bsum[t];
    __syncthreads();
    for (int off = 1; off < 256; off <<= 1) {
        int a = (t >= off) ? sb[t - off] : 0;
        __syncthreads();
        sb[t] += a;
        __syncthreads();
    }
    int bbase = sb[blockIdx.x] - bsum[blockIdx.x];

    int base = blockIdx.x * 1024 + t * 4;
    int loc[4];
    int s = 0;
    #pragma unroll
    for (int j = 0; j < 4; ++j) { loc[j] = cnt[physidx(base + j)]; s += loc[j]; }
    sc[t] = s;
    __syncthreads();
    for (int off = 1; off < 256; off <<= 1) {
        int a = (t >= off) ? sc[t - off] : 0;
        __syncthreads();
        sc[t] += a;
        __syncthreads();
    }
    int run = bbase + sc[t] - s;
    #pragma unroll
    for (int j = 0; j < 4; ++j) { offs[physidx(base + j)] = run; run += loc[j]; }
}

// --------------------------------- place runs (head-merged) into segments
__global__ __launch_bounds__(256) void place_k(float* __restrict__ feat,
                                               int* __restrict__ offs16,
                                               unsigned* __restrict__ rec) {
    int i = blockIdx.x * 256 + threadIdx.x;
    if (i >= NPAIR) return;
    int pix = i / DBINS;
    int d   = i - pix * DBINS;
    float* row = feat + (size_t)pix * ROWF;
    const int* rowI = (const int*)row;
    int r = rowI[105 + d];
    if (r < 0) return;
    if (d > 0 && rowI[105 + d - 1] == r) return;      // not a run head
    float wsum = row[64 + d];
    for (int j = d + 1; j < DBINS && rowI[105 + j] == r; ++j)
        wsum += row[64 + j];
    row[64 + d] = wsum;                               // merged weight at head
    int pos = atomicAdd(&offs16[(pix & 15) * NVOX + r], 1);   // sub-major
    rec[pos] = ((unsigned)pix << 6) | (unsigned)d;
}

// ------------------------------------- entry-parallel segmented combine
__global__ __launch_bounds__(256) void combine_k(const float* __restrict__ feat,
                                                 const int* __restrict__ offs16,
                                                 const unsigned* __restrict__ rec,
                                                 float* __restrict__ bev) {
    int ncnt = offs16[NCNT - 1];
    int lane = threadIdx.x & 63;
    int wave = (blockIdx.x << 2) + (threadIdx.x >> 6);
    int nwav = gridDim.x << 2;
    int nchunk = (ncnt + 31) >> 5;

    for (int ch = wave; ch < nchunk; ch += nwav) {
        int i0 = ch << 5;
        int n  = min(32, ncnt - i0);
        int   rv = -1, pv = 0;
        float wv = 0.0f;
        if (lane < n) {
            unsigned e = rec[i0 + lane];
            pv = (int)(e >> 6);
            int d = (int)(e & 63u);
            const float* row = feat + (size_t)pv * ROWF;
            rv = ((const int*)row)[105 + d];
            wv = row[64 + d];
        }
        float acc = 0.0f;
        if (n == 32) {
            float xv[32];
            #pragma unroll
            for (int j = 0; j < 32; ++j) {
                int pj = __shfl(pv, j, 64);
                xv[j] = feat[(size_t)pj * ROWF + lane];
            }
            #pragma unroll
            for (int j = 0; j < 32; ++j) {
                int   rj = __shfl(rv, j, 64);
                float wj = __shfl(wv, j, 64);
                acc = fmaf(wj, xv[j], acc);
                int rn = __shfl(rv, (j + 1) & 31, 64);
                if (j == 31 || rn != rj) {
                    atomicAdd(&bev[(size_t)rj * COUT + lane], acc);
                    acc = 0.0f;
                }
            }
        } else {
            for (int j = 0; j < n; ++j) {
                int   rj = __shfl(rv, j, 64);
                float wj = __shfl(wv, j, 64);
                int   pj = __shfl(pv, j, 64);
                acc = fmaf(wj, feat[(size_t)pj * ROWF + lane], acc);
                int rn = __shfl(rv, (j + 1) & 31, 64);
                if (j == n - 1 || rn != rj) {
                    atomicAdd(&bev[(size_t)rj * COUT + lane], acc);
                    acc = 0.0f;
                }
            }
        }
    }
}

// -------------------------------------------------------- bev -> out
__global__ __launch_bounds__(256) void transpose_k(const float* __restrict__ bev,
                                                   float* __restrict__ out) {
    __shared__ float t[64][65];
    int r0 = blockIdx.x * 64;
    int c  = threadIdx.x & 63;
    int r4 = threadIdx.x >> 6;
    #pragma unroll
    for (int i = 0; i < 16; ++i) {
        int r = r4 + i * 4;
        t[r][c] = bev[(size_t)(r0 + r) * COUT + c];
    }
    __syncthreads();
    int rl  = threadIdx.x & 63;
    int cc0 = threadIdx.x >> 6;
    #pragma unroll
    for (int i = 0; i < 16; ++i) {
        int ch = cc0 + i * 4;
        out[(size_t)ch * NVOX + r0 + rl] = t[rl][ch];
    }
}

// --------------------------------------------------------------------- launch
extern "C" void kernel_launch(void* const* d_in, const int* in_sizes, int n_in,
                              void* d_out, int out_size, void* d_ws, size_t ws_size,
                              hipStream_t stream) {
    const float* img   = (const float*)d_in[0];
    const float* dw    = (const float*)d_in[1];
    const float* db    = (const float*)d_in[2];
    const float* rots  = (const float*)d_in[3];
    const float* trans = (const float*)d_in[4];
    const float* intr  = (const float*)d_in[5];
    const float* prot  = (const float*)d_in[6];
    const float* ptrn  = (const float*)d_in[7];
    float* out = (float*)d_out;

    char* ws = (char*)d_ws;
    double*   cams   = (double*)ws;
    int*      bsum   = (int*)(ws + WS_BSUM);
    float*    feat   = (float*)(ws + WS_FEAT);
    int*      offs16 = (int*)(ws + WS_OFFS);
    unsigned* rec    = (unsigned*)(ws + WS_REC);
    int*      cnt16  = (int*)(ws + WS_CNT);   // aliases rec (dead before rec use)
    float*    bev    = (float*)(ws + WS_BEV);

    gemm_setup_k<<<GEMM_BLOCKS + ZERO_BLOCKS, 256, 0, stream>>>(
        img, dw, db, feat, rots, trans, intr, prot, ptrn, cams, cnt16, bev);
    phaseA_k<<<NCAM * NPIX / 8, 512, 0, stream>>>(feat, cams, cnt16);
    scan1_k<<<256, 256, 0, stream>>>(cnt16, bsum);
    scan3_k<<<256, 256, 0, stream>>>(cnt16, bsum, offs16);
    place_k<<<(NPAIR + 255) / 256, 256, 0, stream>>>(feat, offs16, rec);
    combine_k<<<3072, 256, 0, stream>>>(feat, offs16, rec, bev);
    transpose_k<<<NVOX / 64, 256, 0, stream>>>(bev, out);
}

// Round 27
// 101.838 us; speedup vs baseline: 1.1232x; 1.0011x over previous
//
#include <hip/hip_runtime.h>
#include <cmath>

#define CIN   512
#define COUT  64
#define DBINS 41
#define NFEAT 105   // DBINS + COUT
#define HF    16
#define WF    44
#define NPIX  704   // HF*WF
#define NCAM  24    // B*N
#define NXG   128
#define NVOX  16384 // 128*128 (NX2 == 1)
#define ROWF  210   // per-pixel feat row
#define NPAIR (NCAM * NPIX * DBINS)  // 692736
#define NSUB  16
#define NCNT  (NVOX * NSUB)          // 262144 sub-counters
#define GEMM_BLOCKS 1848
#define ZERO_BLOCKS 320
#define TOTAL_BLOCKS (GEMM_BLOCKS + ZERO_BLOCKS)   // 2168 = 8 * 271
#define CHUNK_PER_XCD 271

// Counter layout: sub-major (r17). Run-merge at heads (r22). Dense bev (r23).
// Fused setup/zero (r24). GEMM: G=2 + kh split + 7 oh (r24-validated optimum).
// r27: XCD-aware bijective block swizzle — the 14 blocks sharing a pixel
// tile's x panel land on ONE XCD's L2 (FETCH was 2x the x tensor).

// Workspace layout (bytes):
#define WS_BSUM  5120
#define WS_FEAT  8192
#define WS_OFFS  14200832
#define WS_REC   15249408
#define WS_CNT   15249408
#define WS_BEV   18020352

// ---------------------------------------------------------------- utilities
__device__ __forceinline__ void inv3(const double a[9], double o[9]) {
    double c00 =  a[4]*a[8] - a[5]*a[7];
    double c01 = -(a[3]*a[8] - a[5]*a[6]);
    double c02 =  a[3]*a[7] - a[4]*a[6];
    double det = a[0]*c00 + a[1]*c01 + a[2]*c02;
    double id  = 1.0 / det;
    o[0] = c00 * id;
    o[1] = -(a[1]*a[8] - a[2]*a[7]) * id;
    o[2] =  (a[1]*a[5] - a[2]*a[4]) * id;
    o[3] = c01 * id;
    o[4] =  (a[0]*a[8] - a[2]*a[6]) * id;
    o[5] = -(a[0]*a[5] - a[2]*a[3]) * id;
    o[6] = c02 * id;
    o[7] = -(a[0]*a[7] - a[1]*a[6]) * id;
    o[8] =  (a[0]*a[4] - a[1]*a[3]) * id;
}

// --------------------------- 1x1 conv GEMM + fused setup/zero (extra blocks)
// XCD swizzle: hw bid -> lbid = (bid&7)*271 + (bid>>3)  (bijective, 2168=8*271).
// lbid < GEMM_BLOCKS: r21-validated GEMM (M=128/G=2/N=16, kh split, 7 oh).
// lbid >= GEMM_BLOCKS (320): zero cnt16 + bev; first zero-block builds cams.
__global__ __launch_bounds__(256) void gemm_setup_k(const float* __restrict__ x,
                                                    const float* __restrict__ w,
                                                    const float* __restrict__ bias,
                                                    float* __restrict__ feat,
                                                    const float* __restrict__ rots,
                                                    const float* __restrict__ trans,
                                                    const float* __restrict__ intrins,
                                                    const float* __restrict__ post_rots,
                                                    const float* __restrict__ post_trans,
                                                    double* __restrict__ cams,
                                                    int* __restrict__ cnt16,
                                                    float* __restrict__ bev) {
    int lbid = (blockIdx.x & 7) * CHUNK_PER_XCD + (blockIdx.x >> 3);

    if (lbid >= GEMM_BLOCKS) {
        int zb = lbid - GEMM_BLOCKS;            // 0..319
        int4 z = make_int4(0, 0, 0, 0);
        if (zb < 64) {
            int base = (zb * 256 + threadIdx.x) * 16;
            #pragma unroll
            for (int j = 0; j < 4; ++j)
                *reinterpret_cast<int4*>(&cnt16[base + j * 4]) = z;
        } else {
            int base = ((zb - 64) * 256 + threadIdx.x) * 16;
            #pragma unroll
            for (int j = 0; j < 4; ++j)
                *reinterpret_cast<int4*>(&bev[base + j * 4]) = z;
        }
        if (zb == 0 && threadIdx.x < NCAM) {
            int i = threadIdx.x;
            double R[9], K[9], PR[9], Kinv[9], PRinv[9];
            for (int k = 0; k < 9; ++k) {
                R[k]  = (double)rots[i*9 + k];
                K[k]  = (double)intrins[i*9 + k];
                PR[k] = (double)post_rots[i*9 + k];
            }
            inv3(K, Kinv);
            inv3(PR, PRinv);
            double* o = cams + (size_t)i * 24;
            for (int k = 0; k < 9; ++k) o[k] = PRinv[k];
            o[9]  = (double)post_trans[i*3 + 0];
            o[10] = (double)post_trans[i*3 + 1];
            o[11] = (double)post_trans[i*3 + 2];
            for (int r = 0; r < 3; ++r)
                for (int c = 0; c < 3; ++c)
                    o[12 + r*3 + c] = R[r*3+0]*Kinv[0*3+c] + R[r*3+1]*Kinv[1*3+c] + R[r*3+2]*Kinv[2*3+c];
            o[21] = (double)trans[i*3 + 0];
            o[22] = (double)trans[i*3 + 1];
            o[23] = (double)trans[i*3 + 2];
        }
        return;
    }

    __shared__ float smem[4096];

    int bx   = lbid;
    int kh   = bx & 1;
    int oh   = (bx >> 1) % 7;
    int tile = (bx >> 1) / 7;
    int p0g  = tile * 128;
    int lane = threadIdx.x & 63;
    int wid  = threadIdx.x >> 6;
    int obase0 = (oh < 6) ? oh * 16 : 89;

    int og = obase0 + wid * 4;
    const float* wbase = w + (size_t)__builtin_amdgcn_readfirstlane(og) * CIN + kh * 256;

    int spx  = threadIdx.x & 127;
    int skq  = threadIdx.x >> 7;
    int gpix = p0g + spx;
    int sbn  = gpix / NPIX;
    int sp   = gpix - sbn * NPIX;
    const float* gx = x + ((size_t)sbn * CIN + kh * 256) * NPIX + sp;

    float xr[2][4];
    float acc[4][2];
    #pragma unroll
    for (int i = 0; i < 4; ++i)
        #pragma unroll
        for (int j = 0; j < 2; ++j) acc[i][j] = 0.0f;

    #pragma unroll
    for (int q = 0; q < 2; ++q)
        #pragma unroll
        for (int c = 0; c < 4; ++c)
            xr[q][c] = gx[(size_t)((skq + 2 * q) * 4 + c) * NPIX];
    #pragma unroll
    for (int q = 0; q < 2; ++q)
        *reinterpret_cast<float4*>(&smem[((skq + 2 * q) * 128 + spx) * 4]) =
            make_float4(xr[q][0], xr[q][1], xr[q][2], xr[q][3]);
    #pragma unroll
    for (int q = 0; q < 2; ++q)
        #pragma unroll
        for (int c = 0; c < 4; ++c)
            xr[q][c] = gx[(size_t)(16 + (skq + 2 * q) * 4 + c) * NPIX];
    __syncthreads();

    #pragma unroll 1
    for (int kt = 0; kt < 16; ++kt) {
        int cur = kt & 1;
        if (kt < 15) {
            float* xsn = smem + (cur ^ 1) * 2048;
            #pragma unroll
            for (int q = 0; q < 2; ++q)
                *reinterpret_cast<float4*>(&xsn[((skq + 2 * q) * 128 + spx) * 4]) =
                    make_float4(xr[q][0], xr[q][1], xr[q][2], xr[q][3]);
        }
        if (kt < 14) {
            #pragma unroll
            for (int q = 0; q < 2; ++q)
                #pragma unroll
                for (int c = 0; c < 4; ++c)
                    xr[q][c] = gx[(size_t)((kt + 2) * 16 + (skq + 2 * q) * 4 + c) * NPIX];
        }
        const float* xs = smem + cur * 2048;
        const float* wk = wbase + kt * 16;
        #pragma unroll
        for (int kq = 0; kq < 4; ++kq) {
            float4 xv[2];
            #pragma unroll
            for (int j = 0; j < 2; ++j)
                xv[j] = *reinterpret_cast<const float4*>(&xs[(kq * 128 + lane + j * 64) * 4]);
            #pragma unroll
            for (int i = 0; i < 4; ++i) {
                float4 wv = *reinterpret_cast<const float4*>(wk + (size_t)i * CIN + (kq << 2));
                #pragma unroll
                for (int j = 0; j < 2; ++j) {
                    acc[i][j] = fmaf(xv[j].x, wv.x, acc[i][j]);
                    acc[i][j] = fmaf(xv[j].y, wv.y, acc[i][j]);
                    acc[i][j] = fmaf(xv[j].z, wv.z, acc[i][j]);
                    acc[i][j] = fmaf(xv[j].w, wv.w, acc[i][j]);
                }
            }
        }
        __syncthreads();
    }

    float* ep = smem;
    #pragma unroll
    for (int i = 0; i < 4; ++i) {
        int o = obase0 + wid * 4 + i;
        float b = (kh == 0) ? bias[o] : 0.0f;
        #pragma unroll
        for (int j = 0; j < 2; ++j)
            ep[(lane + j * 64) * 17 + wid * 4 + i] = acc[i][j] + b;
    }
    __syncthreads();
    for (int idx = threadIdx.x; idx < 128 * 16; idx += 256) {
        int px = idx >> 4;
        int ol = idx & 15;
        feat[(size_t)(p0g + px) * ROWF + kh * NFEAT + obase0 + ol] = ep[px * 17 + ol];
    }
}

// -------------------------------------------- softmax + geometry, in-place
// 8 independent waves per block (one pixel each); kh fold (r24-validated).
__global__ __launch_bounds__(512) void phaseA_k(float* __restrict__ feat,
                                                const double* __restrict__ cams,
                                                int* __restrict__ cnt16) {
    int wid  = threadIdx.x >> 6;
    int lane = threadIdx.x & 63;
    int pix  = blockIdx.x * 8 + wid;
    int bn   = pix / NPIX;
    int p    = pix - bn * NPIX;
    int h    = p / WF;
    int wpx  = p - h * WF;

    __shared__ float f[8][NFEAT];
    float* row = feat + (size_t)pix * ROWF;
    for (int o = lane; o < NFEAT; o += 64) f[wid][o] = row[o] + row[NFEAT + o];
    __syncthreads();

    float v = (lane < DBINS) ? f[wid][lane] : -1e30f;
    float m = v;
    #pragma unroll
    for (int o = 32; o > 0; o >>= 1) m = fmaxf(m, __shfl_xor(m, o, 64));
    float e = (lane < DBINS) ? expf(v - m) : 0.0f;
    float s = e;
    #pragma unroll
    for (int o = 32; o > 0; o >>= 1) s += __shfl_xor(s, o, 64);

    int   rk = -1;
    float pd = 0.0f;
    if (lane < DBINS) {
        pd = e / s;
        const double* cm = cams + (size_t)bn * 24;
        double dd = 4.0 + (double)lane;
        double ax = (double)wpx - cm[9];
        double ay = (double)h   - cm[10];
        double az = dd          - cm[11];
        double q0 = cm[0]*ax + cm[1]*ay + cm[2]*az;
        double q1 = cm[3]*ax + cm[4]*ay + cm[5]*az;
        double q2 = cm[6]*ax + cm[7]*ay + cm[8]*az;
        double r0 = q0 * q2, r1 = q1 * q2, r2 = q2;
        double sx = cm[12]*r0 + cm[13]*r1 + cm[14]*r2 + cm[21];
        double sy = cm[15]*r0 + cm[16]*r1 + cm[17]*r2 + cm[22];
        double sz = cm[18]*r0 + cm[19]*r1 + cm[20]*r2 + cm[23];
        int cx = (int)((sx + 50.8) / 0.8);   // trunc == .astype(int32)
        int cy = (int)((sy + 50.8) / 0.8);
        int cz = (int)(sz / 20.0);
        bool ok = (cx >= 0) && (cx < NXG) && (cy >= 0) && (cy < NXG) && (cz == 0);
        rk = ok ? (cy * NXG + cx) : -1;
    }
    int  rkprev = __shfl_up(rk, 1, 64);
    bool head   = (rk >= 0) && (lane == 0 || rk != rkprev);

    if (lane < DBINS) {
        row[64 + lane] = pd;
        ((int*)row)[105 + lane] = rk;
    }
    if (head) atomicAdd(&cnt16[(pix & 15) * NVOX + rk], 1);   // sub-major, heads only
    row[lane] = f[wid][DBINS + lane];
}

// ----------------------------------------- scan of 262144 counters (2 stages)
__device__ __forceinline__ int physidx(int l) { return (l & 15) * NVOX + (l >> 4); }

__global__ __launch_bounds__(256) void scan1_k(const int* __restrict__ cnt,
                                               int* __restrict__ bsum) {
    __shared__ int sc[256];
    int t = threadIdx.x;
    int base = blockIdx.x * 1024 + t * 4;
    int s = 0;
    #pragma unroll
    for (int j = 0; j < 4; ++j) s += cnt[physidx(base + j)];
    sc[t] = s;
    __syncthreads();
    for (int off = 128; off > 0; off >>= 1) {
        if (t < off) sc[t] += sc[t + off];
        __syncthreads();
    }
    if (t == 0) bsum[blockIdx.x] = sc[0];
}

__global__ __launch_bounds__(256) void scan3_k(const int* __restrict__ cnt,
                                               const int* __restrict__ bsum,
                                               int* __restrict__ offs) {
    __shared__ int sb[256];
    __shared__ int sc[256];
    int t = threadIdx.x;
    sb[t] = bsum[t];
    __syncthreads();
    for (int off = 1; off < 256; off <<= 1) {
        int a = (t >= off) ? sb[t - off] : 0;
        __syncthreads();
        sb[t] += a;
        __syncthreads();
    }
    int bbase = sb[blockIdx.x] - bsum[blockIdx.x];

    int base = blockIdx.x * 1024 + t * 4;
    int loc[4];
    int s = 0;
    #pragma unroll
    for (int j = 0; j < 4; ++j) { loc[j] = cnt[physidx(base + j)]; s += loc[j]; }
    sc[t] = s;
    __syncthreads();
    for (int off = 1; off < 256; off <<= 1) {
        int a = (t >= off) ? sc[t - off] : 0;
        __syncthreads();
        sc[t] += a;
        __syncthreads();
    }
    int run = bbase + sc[t] - s;
    #pragma unroll
    for (int j = 0; j < 4; ++j) { offs[physidx(base + j)] = run; run += loc[j]; }
}

// --------------------------------- place runs (head-merged) into segments
__global__ __launch_bounds__(256) void place_k(float* __restrict__ feat,
                                               int* __restrict__ offs16,
                                               unsigned* __restrict__ rec) {
    int i = blockIdx.x * 256 + threadIdx.x;
    if (i >= NPAIR) return;
    int pix = i / DBINS;
    int d   = i - pix * DBINS;
    float* row = feat + (size_t)pix * ROWF;
    const int* rowI = (const int*)row;
    int r = rowI[105 + d];
    if (r < 0) return;
    if (d > 0 && rowI[105 + d - 1] == r) return;      // not a run head
    float wsum = row[64 + d];
    for (int j = d + 1; j < DBINS && rowI[105 + j] == r; ++j)
        wsum += row[64 + j];
    row[64 + d] = wsum;                               // merged weight at head
    int pos = atomicAdd(&offs16[(pix & 15) * NVOX + r], 1);   // sub-major
    rec[pos] = ((unsigned)pix << 6) | (unsigned)d;
}

// ------------------------------------- entry-parallel segmented combine
__global__ __launch_bounds__(256) void combine_k(const float* __restrict__ feat,
                                                 const int* __restrict__ offs16,
                                                 const unsigned* __restrict__ rec,
                                                 float* __restrict__ bev) {
    int ncnt = offs16[NCNT - 1];
    int lane = threadIdx.x & 63;
    int wave = (blockIdx.x << 2) + (threadIdx.x >> 6);
    int nwav = gridDim.x << 2;
    int nchunk = (ncnt + 31) >> 5;

    for (int ch = wave; ch < nchunk; ch += nwav) {
        int i0 = ch << 5;
        int n  = min(32, ncnt - i0);
        int   rv = -1, pv = 0;
        float wv = 0.0f;
        if (lane < n) {
            unsigned e = rec[i0 + lane];
            pv = (int)(e >> 6);
            int d = (int)(e & 63u);
            const float* row = feat + (size_t)pv * ROWF;
            rv = ((const int*)row)[105 + d];
            wv = row[64 + d];
        }
        float acc = 0.0f;
        if (n == 32) {
            float xv[32];
            #pragma unroll
            for (int j = 0; j < 32; ++j) {
                int pj = __shfl(pv, j, 64);
                xv[j] = feat[(size_t)pj * ROWF + lane];
            }
            #pragma unroll
            for (int j = 0; j < 32; ++j) {
                int   rj = __shfl(rv, j, 64);
                float wj = __shfl(wv, j, 64);
                acc = fmaf(wj, xv[j], acc);
                int rn = __shfl(rv, (j + 1) & 31, 64);
                if (j == 31 || rn != rj) {
                    atomicAdd(&bev[(size_t)rj * COUT + lane], acc);
                    acc = 0.0f;
                }
            }
        } else {
            for (int j = 0; j < n; ++j) {
                int   rj = __shfl(rv, j, 64);
                float wj = __shfl(wv, j, 64);
                int   pj = __shfl(pv, j, 64);
                acc = fmaf(wj, feat[(size_t)pj * ROWF + lane], acc);
                int rn = __shfl(rv, (j + 1) & 31, 64);
                if (j == n - 1 || rn != rj) {
                    atomicAdd(&bev[(size_t)rj * COUT + lane], acc);
                    acc = 0.0f;
                }
            }
        }
    }
}

// -------------------------------------------------------- bev -> out
__global__ __launch_bounds__(256) void transpose_k(const float* __restrict__ bev,
                                                   float* __restrict__ out) {
    __shared__ float t[64][65];
    int r0 = blockIdx.x * 64;
    int c  = threadIdx.x & 63;
    int r4 = threadIdx.x >> 6;
    #pragma unroll
    for (int i = 0; i < 16; ++i) {
        int r = r4 + i * 4;
        t[r][c] = bev[(size_t)(r0 + r) * COUT + c];
    }
    __syncthreads();
    int rl  = threadIdx.x & 63;
    int cc0 = threadIdx.x >> 6;
    #pragma unroll
    for (int i = 0; i < 16; ++i) {
        int ch = cc0 + i * 4;
        out[(size_t)ch * NVOX + r0 + rl] = t[rl][ch];
    }
}

// --------------------------------------------------------------------- launch
extern "C" void kernel_launch(void* const* d_in, const int* in_sizes, int n_in,
                              void* d_out, int out_size, void* d_ws, size_t ws_size,
                              hipStream_t stream) {
    const float* img   = (const float*)d_in[0];
    const float* dw    = (const float*)d_in[1];
    const float* db    = (const float*)d_in[2];
    const float* rots  = (const float*)d_in[3];
    const float* trans = (const float*)d_in[4];
    const float* intr  = (const float*)d_in[5];
    const float* prot  = (const float*)d_in[6];
    const float* ptrn  = (const float*)d_in[7];
    float* out = (float*)d_out;

    char* ws = (char*)d_ws;
    double*   cams   = (double*)ws;
    int*      bsum   = (int*)(ws + WS_BSUM);
    float*    feat   = (float*)(ws + WS_FEAT);
    int*      offs16 = (int*)(ws + WS_OFFS);
    unsigned* rec    = (unsigned*)(ws + WS_REC);
    int*      cnt16  = (int*)(ws + WS_CNT);   // aliases rec (dead before rec use)
    float*    bev    = (float*)(ws + WS_BEV);

    gemm_setup_k<<<TOTAL_BLOCKS, 256, 0, stream>>>(
        img, dw, db, feat, rots, trans, intr, prot, ptrn, cams, cnt16, bev);
    phaseA_k<<<NCAM * NPIX / 8, 512, 0, stream>>>(feat, cams, cnt16);
    scan1_k<<<256, 256, 0, stream>>>(cnt16, bsum);
    scan3_k<<<256, 256, 0, stream>>>(cnt16, bsum, offs16);
    place_k<<<(NPAIR + 255) / 256, 256, 0, stream>>>(feat, offs16, rec);
    combine_k<<<3072, 256, 0, stream>>>(feat, offs16, rec, bev);
    transpose_k<<<NVOX / 64, 256, 0, stream>>>(bev, out);
}